// Round 3
// baseline (63.862 us; speedup 1.0000x reference)
//
#include <hip/hip_runtime.h>

// Depthwise xcorr: out[p][oy][ox] = sum_{ky,kx} x[p][oy+ky][ox+kx] * z[p][ky][kx]
// p = b*C+c plane index, 32768 planes. x: 31x31, z: 7x7, out: 25x25, all fp32.
// (Round 2 resubmission — rounds 1 and 2 both died on UnresponsiveContainer
//  before compile/run; kernel has never executed.)

#define PLANES_PER_BLOCK 10
#define HX 31
#define WX 31
#define HZ 7
#define WZ 7
#define HO 25
#define WO 25
#define XPLANE (HX * WX)   // 961
#define ZPLANE (HZ * WZ)   // 49
#define OPLANE (HO * WO)   // 625
#define ROWSTRIDE 39       // padded LDS row stride, 39 mod 32 = 7 -> bank-spread
#define LDSPLANE (HX * ROWSTRIDE)  // 1209

__global__ __launch_bounds__(256) void dwxcorr_kernel(
    const float* __restrict__ z, const float* __restrict__ x,
    float* __restrict__ out, int nplanes) {
  __shared__ float xs[PLANES_PER_BLOCK * LDSPLANE];  // 48360 B
  __shared__ float zs[PLANES_PER_BLOCK * ZPLANE];    //  1960 B

  const int tid = threadIdx.x;
  const int p0 = blockIdx.x * PLANES_PER_BLOCK;
  const int pmax = min(PLANES_PER_BLOCK, nplanes - p0);

  // ---- stage x (contiguous global region -> padded LDS) ----
  const int nx = pmax * XPLANE;
  const size_t xoff = (size_t)p0 * XPLANE;
  for (int i = tid; i < nx; i += 256) {
    int pp = i / XPLANE;
    int rem = i - pp * XPLANE;
    int r = rem / WX;
    int c = rem - r * WX;
    xs[pp * LDSPLANE + r * ROWSTRIDE + c] = x[xoff + i];
  }
  // ---- stage z ----
  const int nz = pmax * ZPLANE;
  const size_t zoff = (size_t)p0 * ZPLANE;
  for (int i = tid; i < nz; i += 256) {
    zs[i] = z[zoff + i];
  }
  __syncthreads();

  // ---- compute: thread -> (plane pp, 5x5 output tile (ty,tx)) ----
  const int pp = tid / 25;
  if (pp >= pmax) return;  // threads 250..255 (and partial last block) idle
  const int t25 = tid - pp * 25;
  const int ty = t25 / 5;
  const int tx = t25 - ty * 5;

  // z plane -> registers (broadcast reads, <=3 distinct addrs per wave)
  float zr[ZPLANE];
#pragma unroll
  for (int j = 0; j < ZPLANE; ++j) zr[j] = zs[pp * ZPLANE + j];

  float acc[5][5];
#pragma unroll
  for (int r = 0; r < 5; ++r)
#pragma unroll
    for (int j = 0; j < 5; ++j) acc[r][j] = 0.0f;

  const float* xbase = &xs[pp * LDSPLANE + (ty * 5) * ROWSTRIDE + tx * 5];

  // Stream 11 x-rows; each row contributes to output rows orow = iy-ky in [0,4]
#pragma unroll
  for (int iy = 0; iy < 11; ++iy) {
    float xr[11];
#pragma unroll
    for (int k = 0; k < 11; ++k) xr[k] = xbase[iy * ROWSTRIDE + k];
    const int ky_lo = (iy - 4 < 0) ? 0 : iy - 4;
    const int ky_hi = (iy < 6) ? iy : 6;
#pragma unroll
    for (int ky = 0; ky < 7; ++ky) {
      if (ky < ky_lo || ky > ky_hi) continue;  // folds at compile time
      const int orow = iy - ky;
#pragma unroll
      for (int kx = 0; kx < 7; ++kx) {
        const float zv = zr[ky * 7 + kx];
#pragma unroll
        for (int j = 0; j < 5; ++j)
          acc[orow][j] = fmaf(xr[kx + j], zv, acc[orow][j]);
      }
    }
  }

  // ---- write 5x5 tile ----
  float* obase = &out[(size_t)(p0 + pp) * OPLANE + (ty * 5) * WO + tx * 5];
#pragma unroll
  for (int r = 0; r < 5; ++r)
#pragma unroll
    for (int j = 0; j < 5; ++j) obase[r * WO + j] = acc[r][j];
}

extern "C" void kernel_launch(void* const* d_in, const int* in_sizes, int n_in,
                              void* d_out, int out_size, void* d_ws, size_t ws_size,
                              hipStream_t stream) {
  const float* z = (const float*)d_in[0];  // [B,C,7,7]
  const float* x = (const float*)d_in[1];  // [B,C,31,31]
  float* out = (float*)d_out;              // [B,C,25,25]

  const int nplanes = in_sizes[0] / ZPLANE;  // 128*256 = 32768
  const int blocks = (nplanes + PLANES_PER_BLOCK - 1) / PLANES_PER_BLOCK;

  hipLaunchKernelGGL(dwxcorr_kernel, dim3(blocks), dim3(256), 0, stream,
                     z, x, out, nplanes);
}